// Round 7
// baseline (1064.961 us; speedup 1.0000x reference)
//
#include <hip/hip_runtime.h>

#define LNEPS 1e-5f
#define AEPS 1e-8f
#define SCALE_Q 0.036084391824351615f  // 768^-0.5

// ---------------- transpose 768x768 fp32: WT[c][i] = W[i][c] ----------------
__global__ void packT_k(const float* __restrict__ W, float* __restrict__ WT) {
  __shared__ float tile[32][33];
  int c0 = blockIdx.x * 32, i0 = blockIdx.y * 32;
  int tx = threadIdx.x & 31, ty = threadIdx.x >> 5;  // 32x8
#pragma unroll
  for (int k = 0; k < 4; ++k)
    tile[ty + 8 * k][tx] = W[(size_t)(i0 + ty + 8 * k) * 768 + c0 + tx];
  __syncthreads();
#pragma unroll
  for (int k = 0; k < 4; ++k)
    WT[(size_t)(c0 + ty + 8 * k) * 768 + i0 + tx] = tile[tx][ty + 8 * k];
}

// ---------------- broadcast slots to all batch rows ----------------
__global__ void init_slots_k(const float* __restrict__ s0, float* __restrict__ slots) {
  int idx = blockIdx.x * 256 + threadIdx.x;  // 196608
  slots[idx] = s0[idx % 6144];
}

// ---------------- generic batched GEMV, split-k x4, 1024 threads ----------------
// out[256,768] = f(X[256,768] @ W[768,768]); grid (12 colblk, 16 rowblk).
// MODE 0: acc+bias | 1: acc | 2: alpha[r]*acc+beta[r]*bias | 3: relu(acc+bias) | 4: out+=acc+bias
template <bool LN, int MODE>
__global__ void gemv_k(const float* __restrict__ X, const float* __restrict__ W,
                       const float* __restrict__ bias, const float* __restrict__ gamma,
                       const float* __restrict__ beta_ln, const float* __restrict__ alpha,
                       const float* __restrict__ beta, float* __restrict__ out) {
  __shared__ float Xs[16][772];
  __shared__ float sm[16], sr[16];
  int c0 = blockIdx.x * 64, r0 = blockIdx.y * 16, t = threadIdx.x;
#pragma unroll
  for (int j = 0; j < 3; ++j) {
    int fidx = j * 1024 + t;
    int r = fidx / 192, c4 = fidx % 192;
    *(float4*)&Xs[r][c4 * 4] = *(const float4*)(X + (size_t)(r0 + r) * 768 + c4 * 4);
  }
  __syncthreads();
  if (LN) {
    if (t < 256) {
      int w = t >> 6, l = t & 63;
#pragma unroll
      for (int j = 0; j < 4; ++j) {
        int r = w * 4 + j;
        float s = 0.f, ss = 0.f;
#pragma unroll
        for (int m2 = 0; m2 < 12; ++m2) { float x = Xs[r][l + 64 * m2]; s += x; ss += x * x; }
#pragma unroll
        for (int o = 32; o; o >>= 1) { s += __shfl_xor(s, o); ss += __shfl_xor(ss, o); }
        if (l == 0) {
          float mu = s * (1.f / 768.f);
          sm[r] = mu;
          sr[r] = rsqrtf(ss * (1.f / 768.f) - mu * mu + LNEPS);
        }
      }
    }
    __syncthreads();
#pragma unroll
    for (int j = 0; j < 12; ++j) {
      int idx = j * 1024 + t;
      int r = idx / 768, d = idx % 768;
      Xs[r][d] = (Xs[r][d] - sm[r]) * sr[r] * gamma[d] + beta_ln[d];
    }
    __syncthreads();
  }
  int cx = t & 15, rw = (t >> 4) & 15, kg = t >> 8;
  int c = c0 + cx * 4;
  float ax = 0.f, ay = 0.f, az = 0.f, aw = 0.f;
  const float* wp = W + c;
  int k0 = kg * 192;
  for (int k = k0; k < k0 + 192; k += 4) {
#pragma unroll
    for (int kk = 0; kk < 4; ++kk) {
      float4 wv = *(const float4*)(wp + (size_t)(k + kk) * 768);
      float xv = Xs[rw][k + kk];
      ax += xv * wv.x; ay += xv * wv.y; az += xv * wv.z; aw += xv * wv.w;
    }
  }
  __syncthreads();  // all kg done reading Xs; reuse as reduce buffer
  float* red = (float*)Xs;
  if (kg > 0) {
    float4 v; v.x = ax; v.y = ay; v.z = az; v.w = aw;
    *(float4*)&red[(size_t)(((kg - 1) * 256 + rw * 16 + cx)) * 4] = v;
  }
  __syncthreads();
  if (kg == 0) {
#pragma unroll
    for (int g = 1; g < 4; ++g) {
      float4 v = *(const float4*)&red[(size_t)(((g - 1) * 256 + rw * 16 + cx)) * 4];
      ax += v.x; ay += v.y; az += v.z; aw += v.w;
    }
    int rr = r0 + rw;
    size_t oidx = (size_t)rr * 768 + c;
    float4 res;
    if (MODE == 0) {
      float4 b4 = *(const float4*)(bias + c);
      res.x = ax + b4.x; res.y = ay + b4.y; res.z = az + b4.z; res.w = aw + b4.w;
    } else if (MODE == 1) {
      res.x = ax; res.y = ay; res.z = az; res.w = aw;
    } else if (MODE == 2) {
      float4 b4 = *(const float4*)(bias + c);
      float al = alpha[rr], be = beta[rr];
      res.x = ax * al + b4.x * be; res.y = ay * al + b4.y * be;
      res.z = az * al + b4.z * be; res.w = aw * al + b4.w * be;
    } else if (MODE == 3) {
      float4 b4 = *(const float4*)(bias + c);
      res.x = fmaxf(ax + b4.x, 0.f); res.y = fmaxf(ay + b4.y, 0.f);
      res.z = fmaxf(az + b4.z, 0.f); res.w = fmaxf(aw + b4.w, 0.f);
    } else {
      float4 b4 = *(const float4*)(bias + c);
      float4 old = *(const float4*)(out + oidx);
      res.x = old.x + ax + b4.x; res.y = old.y + ay + b4.y;
      res.z = old.z + az + b4.z; res.w = old.w + aw + b4.w;
    }
    *(float4*)(out + oidx) = res;
  }
}

// ---------------- per-slot scalars: Sq = qk.g_in ; c0 = qk.b_in + q.bk ----------------
__global__ void qprep_k(const float* __restrict__ q, const float* __restrict__ qk,
                        const float* __restrict__ g_in, const float* __restrict__ b_in,
                        const float* __restrict__ bk, float* __restrict__ Sqbuf,
                        float* __restrict__ c0buf) {
  int row = blockIdx.x * 4 + (threadIdx.x >> 6), l = threadIdx.x & 63;
  float aS = 0.f, aC = 0.f;
#pragma unroll
  for (int j = 0; j < 12; ++j) {
    int d = l + 64 * j;
    float qkv = qk[(size_t)row * 768 + d];
    aS += qkv * g_in[d];
    aC += qkv * b_in[d] + q[(size_t)row * 768 + d] * bk[d];
  }
#pragma unroll
  for (int o = 32; o; o >>= 1) { aS += __shfl_xor(aS, o); aC += __shfl_xor(aC, o); }
  if (l == 0) { Sqbuf[row] = aS; c0buf[row] = aC; }
}

// ---------------- dots+softmax over raw x; writes attn, w=a*r, rmu=r*mu ----------------
// grid (64 chunk, 32 b), 256 thr = 4 waves x 4 rows
__global__ void __launch_bounds__(256, 6)
dots_k(const float* __restrict__ in, const float* __restrict__ qk,
       const float* __restrict__ g_in, const float* __restrict__ Sqbuf,
       const float* __restrict__ c0buf, float* __restrict__ attnbuf,
       float* __restrict__ wbuf, float* __restrict__ rmubuf) {
  __shared__ float qkgs[8][768];
  __shared__ float c0s[8], Sqs[8];
  int chunk = blockIdx.x, b = blockIdx.y, t = threadIdx.x, w = t >> 6, l = t & 63;
#pragma unroll
  for (int s2 = 0; s2 < 8; ++s2)
    for (int d = t; d < 768; d += 256)
      qkgs[s2][d] = qk[(size_t)b * 6144 + s2 * 768 + d] * g_in[d];
  if (t < 8) { c0s[t] = c0buf[b * 8 + t]; Sqs[t] = Sqbuf[b * 8 + t]; }
  __syncthreads();
  for (int rr = 0; rr < 4; ++rr) {
    int n = chunk * 16 + w * 4 + rr;
    size_t row = (size_t)b * 1024 + n;
    const float* xp = in + row * 768;
    float v[12], s = 0.f, ss = 0.f;
#pragma unroll
    for (int j = 0; j < 12; ++j) { v[j] = xp[l + 64 * j]; s += v[j]; ss += v[j] * v[j]; }
#pragma unroll
    for (int o = 32; o; o >>= 1) { s += __shfl_xor(s, o); ss += __shfl_xor(ss, o); }
    float mu = s * (1.f / 768.f), r = rsqrtf(ss * (1.f / 768.f) - mu * mu + LNEPS);
    float ds[8] = {};
#pragma unroll
    for (int j = 0; j < 12; ++j) {
      float xv = v[j];
      int d = l + 64 * j;
#pragma unroll
      for (int s2 = 0; s2 < 8; ++s2) ds[s2] += qkgs[s2][d] * xv;
    }
#pragma unroll
    for (int s2 = 0; s2 < 8; ++s2)
#pragma unroll
      for (int o = 32; o; o >>= 1) ds[s2] += __shfl_xor(ds[s2], o);
    float rmu = r * mu;
    float sc[8];
#pragma unroll
    for (int s2 = 0; s2 < 8; ++s2)
      sc[s2] = (r * ds[s2] - rmu * Sqs[s2] + c0s[s2]) * SCALE_Q;
    float mx = sc[0];
#pragma unroll
    for (int s2 = 1; s2 < 8; ++s2) mx = fmaxf(mx, sc[s2]);
    float e[8], se = 0.f;
#pragma unroll
    for (int s2 = 0; s2 < 8; ++s2) { e[s2] = expf(sc[s2] - mx); se += e[s2]; }
    float inv_se = 1.f / se;
    if (l == 0) {
#pragma unroll
      for (int s2 = 0; s2 < 8; ++s2) {
        float a = e[s2] * inv_se;
        attnbuf[row * 8 + s2] = a;
        wbuf[row * 8 + s2] = a * r;
      }
    }
    if (l == 1) rmubuf[row] = rmu;
  }
}

// ---------------- deterministic A0/A1 reduce: A0=sum a, A1=sum a*rmu ----------------
// grid 32 (per b), 256 thr
__global__ void A_reduce_k(const float* __restrict__ attnbuf, const float* __restrict__ rmubuf,
                           float* __restrict__ gA0, float* __restrict__ gA1) {
  __shared__ float r0s[256], r1s[256];
  int b = blockIdx.x, t = threadIdx.x;
  float a0 = 0.f, a1 = 0.f;
  for (int j = 0; j < 32; ++j) {
    float a = attnbuf[(size_t)b * 8192 + j * 256 + t];
    float rm = rmubuf[b * 1024 + j * 32 + (t >> 3)];
    a0 += a; a1 += a * rm;
  }
  r0s[t] = a0; r1s[t] = a1;
  __syncthreads();
  if (t < 8) {
    float s0 = 0.f, s1 = 0.f;
    for (int k = 0; k < 32; ++k) { s0 += r0s[t + 8 * k]; s1 += r1s[t + 8 * k]; }
    gA0[b * 8 + t] = s0; gA1[b * 8 + t] = s1;
  }
}

// ---------------- pool raw x with weights w: partials[chunk][b*8+s][768] ----------------
// grid (32 chunk, 32 b), 256 thr
__global__ void pool_k(const float* __restrict__ in, const float* __restrict__ wbuf,
                       float* __restrict__ partials) {
  __shared__ float ws[32][8];
  int chunk = blockIdx.x, b = blockIdx.y, t = threadIdx.x;
  ((float*)ws)[t] = wbuf[((size_t)b * 1024 + chunk * 32) * 8 + t];
  __syncthreads();
  float acc[8][3] = {};
  const float* xp = in + ((size_t)b * 1024 + chunk * 32) * 768;
  for (int nn = 0; nn < 32; ++nn) {
    float x0 = xp[(size_t)nn * 768 + t];
    float x1 = xp[(size_t)nn * 768 + t + 256];
    float x2 = xp[(size_t)nn * 768 + t + 512];
#pragma unroll
    for (int s2 = 0; s2 < 8; ++s2) {
      float wv = ws[nn][s2];
      acc[s2][0] += wv * x0; acc[s2][1] += wv * x1; acc[s2][2] += wv * x2;
    }
  }
#pragma unroll
  for (int s2 = 0; s2 < 8; ++s2) {
    size_t base = ((size_t)(chunk * 256 + b * 8 + s2)) * 768;
    partials[base + t] = acc[s2][0];
    partials[base + t + 256] = acc[s2][1];
    partials[base + t + 512] = acc[s2][2];
  }
}

// ---------------- reduce partials + LN-fixup -> pooled ; inv, rho ----------------
__global__ void reduce_fix_k(const float* __restrict__ partials, const float* __restrict__ gA0,
                             const float* __restrict__ gA1, const float* __restrict__ g_in,
                             const float* __restrict__ b_in, float* __restrict__ pooled,
                             float* __restrict__ invbuf, float* __restrict__ rhobuf) {
  int row = blockIdx.x, t = threadIdx.x;  // row = b*8+s
  float A0 = gA0[row], A1 = gA1[row];
#pragma unroll
  for (int c = 0; c < 3; ++c) {
    int d = t + 256 * c;
    float a = 0.f;
    for (int ch = 0; ch < 32; ++ch) a += partials[((size_t)(ch * 256 + row)) * 768 + d];
    pooled[(size_t)row * 768 + d] = g_in[d] * (a - A1) + b_in[d] * A0;
  }
  if (t == 0) {
    float iv = 1.f / (A0 + AEPS);
    invbuf[row] = iv;
    rhobuf[row] = A0 * iv;
  }
}

// ---------------- output writers (fp32) ----------------
__global__ void out_slots_k(const float* __restrict__ slots, float* __restrict__ out) {
  int i = blockIdx.x * 256 + threadIdx.x;  // 196608
  out[i] = slots[i];
}
__global__ void out_attn_k(const float* __restrict__ attnbuf, const float* __restrict__ invbuf,
                           float* __restrict__ out) {
  int i = blockIdx.x * 256 + threadIdx.x;  // 262144 ; layout [b][n][s]
  out[196608 + i] = attnbuf[i] * invbuf[((i >> 13) << 3) + (i & 7)];
}

extern "C" void kernel_launch(void* const* d_in, const int* in_sizes, int n_in,
                              void* d_out, int out_size, void* d_ws, size_t ws_size,
                              hipStream_t stream) {
  (void)in_sizes; (void)n_in; (void)out_size; (void)ws_size;
  const float* slots0 = (const float*)d_in[0];
  const float* inputs = (const float*)d_in[1];
  const float* Wq = (const float*)d_in[2];
  const float* bq = (const float*)d_in[3];
  const float* Wk = (const float*)d_in[4];
  const float* bk = (const float*)d_in[5];
  const float* Wv = (const float*)d_in[6];
  const float* bv = (const float*)d_in[7];
  const float* g_in = (const float*)d_in[8];
  const float* b_in = (const float*)d_in[9];
  const float* g_s = (const float*)d_in[10];
  const float* b_s = (const float*)d_in[11];
  const float* g_ff = (const float*)d_in[12];
  const float* b_ff = (const float*)d_in[13];
  const float* W1 = (const float*)d_in[14];
  const float* b1 = (const float*)d_in[15];
  const float* W2 = (const float*)d_in[16];
  const float* b2 = (const float*)d_in[17];

  char* p = (char*)d_ws;
  float* WkT = (float*)p;      p += (size_t)768 * 768 * 4;
  float* slotsf = (float*)p;   p += 256 * 768 * 4;
  float* qbuf = (float*)p;     p += 256 * 768 * 4;
  float* qkbuf = (float*)p;    p += 256 * 768 * 4;
  float* Sqbuf = (float*)p;    p += 256 * 4;
  float* c0buf = (float*)p;    p += 256 * 4;
  float* attnbuf = (float*)p;  p += (size_t)32768 * 8 * 4;
  float* wbuf = (float*)p;     p += (size_t)32768 * 8 * 4;
  float* rmubuf = (float*)p;   p += 32768 * 4;
  float* partials = (float*)p; p += (size_t)32 * 256 * 768 * 4;
  float* gA0 = (float*)p;      p += 256 * 4;
  float* gA1 = (float*)p;      p += 256 * 4;
  float* pooled = (float*)p;   p += 256 * 768 * 4;
  float* invbuf = (float*)p;   p += 256 * 4;
  float* rhobuf = (float*)p;   p += 256 * 4;
  float* updbuf = (float*)p;   p += 256 * 768 * 4;
  float* t1buf = (float*)p;    p += 256 * 768 * 4;

  dim3 ggrid(12, 16);
  packT_k<<<dim3(24, 24), 256, 0, stream>>>(Wk, WkT);
  init_slots_k<<<768, 256, 0, stream>>>(slots0, slotsf);
  for (int it = 0; it < 3; ++it) {
    gemv_k<true, 0><<<ggrid, 1024, 0, stream>>>(slotsf, Wq, bq, g_s, b_s, nullptr, nullptr, qbuf);
    gemv_k<false, 1><<<ggrid, 1024, 0, stream>>>(qbuf, WkT, nullptr, nullptr, nullptr, nullptr,
                                                 nullptr, qkbuf);
    qprep_k<<<64, 256, 0, stream>>>(qbuf, qkbuf, g_in, b_in, bk, Sqbuf, c0buf);
    dots_k<<<dim3(64, 32), 256, 0, stream>>>(inputs, qkbuf, g_in, Sqbuf, c0buf, attnbuf, wbuf,
                                             rmubuf);
    A_reduce_k<<<32, 256, 0, stream>>>(attnbuf, rmubuf, gA0, gA1);
    pool_k<<<dim3(32, 32), 256, 0, stream>>>(inputs, wbuf, partials);
    reduce_fix_k<<<256, 256, 0, stream>>>(partials, gA0, gA1, g_in, b_in, pooled, invbuf,
                                          rhobuf);
    gemv_k<false, 2><<<ggrid, 1024, 0, stream>>>(pooled, Wv, bv, nullptr, nullptr, invbuf,
                                                 rhobuf, updbuf);
    gemv_k<true, 3><<<ggrid, 1024, 0, stream>>>(updbuf, W1, b1, g_ff, b_ff, nullptr, nullptr,
                                                t1buf);
    gemv_k<false, 4><<<ggrid, 1024, 0, stream>>>(t1buf, W2, b2, nullptr, nullptr, nullptr,
                                                 nullptr, slotsf);
  }
  out_slots_k<<<768, 256, 0, stream>>>(slotsf, (float*)d_out);
  out_attn_k<<<1024, 256, 0, stream>>>(attnbuf, invbuf, (float*)d_out);
}

// Round 8
// 715.566 us; speedup vs baseline: 1.4883x; 1.4883x over previous
//
#include <hip/hip_runtime.h>

#define LNEPS 1e-5f
#define AEPS 1e-8f
#define SCALE_Q 0.036084391824351615f  // 768^-0.5

typedef unsigned int uint32;

__device__ inline unsigned short bfb(float f) {
  __bf16 h = (__bf16)f;
  unsigned short u;
  __builtin_memcpy(&u, &h, 2);
  return u;
}

// ---------------- one-time: cast inputs fp32 -> packed bf16 (uint = 2 elems) ----------------
__global__ void cast_k(const float* __restrict__ in, uint32* __restrict__ xh) {
  size_t i = (size_t)blockIdx.x * 256 + threadIdx.x;  // 6291456 float4s
  float4 v = ((const float4*)in)[i];
  uint2 o;
  o.x = (uint32)bfb(v.x) | ((uint32)bfb(v.y) << 16);
  o.y = (uint32)bfb(v.z) | ((uint32)bfb(v.w) << 16);
  ((uint2*)xh)[i] = o;
}

// ---------------- transpose 768x768 fp32: WT[c][i] = W[i][c] ----------------
__global__ void packT_k(const float* __restrict__ W, float* __restrict__ WT) {
  __shared__ float tile[32][33];
  int c0 = blockIdx.x * 32, i0 = blockIdx.y * 32;
  int tx = threadIdx.x & 31, ty = threadIdx.x >> 5;  // 32x8
#pragma unroll
  for (int k = 0; k < 4; ++k)
    tile[ty + 8 * k][tx] = W[(size_t)(i0 + ty + 8 * k) * 768 + c0 + tx];
  __syncthreads();
#pragma unroll
  for (int k = 0; k < 4; ++k)
    WT[(size_t)(c0 + ty + 8 * k) * 768 + i0 + tx] = tile[tx][ty + 8 * k];
}

// ---------------- broadcast slots to all batch rows ----------------
__global__ void init_slots_k(const float* __restrict__ s0, float* __restrict__ slots) {
  int idx = blockIdx.x * 256 + threadIdx.x;  // 196608
  slots[idx] = s0[idx % 6144];
}

// ---------------- generic batched GEMV, split-k x4, 1024 threads ----------------
// MODE 0: acc+bias | 1: acc | 2: alpha[r]*acc+beta[r]*bias | 3: relu(acc+bias) | 4: out+=acc+bias
template <bool LN, int MODE>
__global__ void gemv_k(const float* __restrict__ X, const float* __restrict__ W,
                       const float* __restrict__ bias, const float* __restrict__ gamma,
                       const float* __restrict__ beta_ln, const float* __restrict__ alpha,
                       const float* __restrict__ beta, float* __restrict__ out) {
  __shared__ float Xs[16][772];
  __shared__ float sm[16], sr[16];
  int c0 = blockIdx.x * 64, r0 = blockIdx.y * 16, t = threadIdx.x;
#pragma unroll
  for (int j = 0; j < 3; ++j) {
    int fidx = j * 1024 + t;
    int r = fidx / 192, c4 = fidx % 192;
    *(float4*)&Xs[r][c4 * 4] = *(const float4*)(X + (size_t)(r0 + r) * 768 + c4 * 4);
  }
  __syncthreads();
  if (LN) {
    if (t < 256) {
      int w = t >> 6, l = t & 63;
#pragma unroll
      for (int j = 0; j < 4; ++j) {
        int r = w * 4 + j;
        float s = 0.f, ss = 0.f;
#pragma unroll
        for (int m2 = 0; m2 < 12; ++m2) { float x = Xs[r][l + 64 * m2]; s += x; ss += x * x; }
#pragma unroll
        for (int o = 32; o; o >>= 1) { s += __shfl_xor(s, o); ss += __shfl_xor(ss, o); }
        if (l == 0) {
          float mu = s * (1.f / 768.f);
          sm[r] = mu;
          sr[r] = rsqrtf(ss * (1.f / 768.f) - mu * mu + LNEPS);
        }
      }
    }
    __syncthreads();
#pragma unroll
    for (int j = 0; j < 12; ++j) {
      int idx = j * 1024 + t;
      int r = idx / 768, d = idx % 768;
      Xs[r][d] = (Xs[r][d] - sm[r]) * sr[r] * gamma[d] + beta_ln[d];
    }
    __syncthreads();
  }
  int cx = t & 15, rw = (t >> 4) & 15, kg = t >> 8;
  int c = c0 + cx * 4;
  float ax = 0.f, ay = 0.f, az = 0.f, aw = 0.f;
  const float* wp = W + c;
  int k0 = kg * 192;
  for (int k = k0; k < k0 + 192; k += 4) {
#pragma unroll
    for (int kk = 0; kk < 4; ++kk) {
      float4 wv = *(const float4*)(wp + (size_t)(k + kk) * 768);
      float xv = Xs[rw][k + kk];
      ax += xv * wv.x; ay += xv * wv.y; az += xv * wv.z; aw += xv * wv.w;
    }
  }
  __syncthreads();  // all kg done reading Xs; reuse as reduce buffer
  float* red = (float*)Xs;
  if (kg > 0) {
    float4 v; v.x = ax; v.y = ay; v.z = az; v.w = aw;
    *(float4*)&red[(size_t)(((kg - 1) * 256 + rw * 16 + cx)) * 4] = v;
  }
  __syncthreads();
  if (kg == 0) {
#pragma unroll
    for (int g = 1; g < 4; ++g) {
      float4 v = *(const float4*)&red[(size_t)(((g - 1) * 256 + rw * 16 + cx)) * 4];
      ax += v.x; ay += v.y; az += v.z; aw += v.w;
    }
    int rr = r0 + rw;
    size_t oidx = (size_t)rr * 768 + c;
    float4 res;
    if (MODE == 0) {
      float4 b4 = *(const float4*)(bias + c);
      res.x = ax + b4.x; res.y = ay + b4.y; res.z = az + b4.z; res.w = aw + b4.w;
    } else if (MODE == 1) {
      res.x = ax; res.y = ay; res.z = az; res.w = aw;
    } else if (MODE == 2) {
      float4 b4 = *(const float4*)(bias + c);
      float al = alpha[rr], be = beta[rr];
      res.x = ax * al + b4.x * be; res.y = ay * al + b4.y * be;
      res.z = az * al + b4.z * be; res.w = aw * al + b4.w * be;
    } else if (MODE == 3) {
      float4 b4 = *(const float4*)(bias + c);
      res.x = fmaxf(ax + b4.x, 0.f); res.y = fmaxf(ay + b4.y, 0.f);
      res.z = fmaxf(az + b4.z, 0.f); res.w = fmaxf(aw + b4.w, 0.f);
    } else {
      float4 b4 = *(const float4*)(bias + c);
      float4 old = *(const float4*)(out + oidx);
      res.x = old.x + ax + b4.x; res.y = old.y + ay + b4.y;
      res.z = old.z + az + b4.z; res.w = old.w + aw + b4.w;
    }
    *(float4*)(out + oidx) = res;
  }
}

// ---------------- per-slot scalars: Sq = qk.g_in ; c0 = qk.b_in + q.bk ----------------
__global__ void qprep_k(const float* __restrict__ q, const float* __restrict__ qk,
                        const float* __restrict__ g_in, const float* __restrict__ b_in,
                        const float* __restrict__ bk, float* __restrict__ Sqbuf,
                        float* __restrict__ c0buf) {
  int row = blockIdx.x * 4 + (threadIdx.x >> 6), l = threadIdx.x & 63;
  float aS = 0.f, aC = 0.f;
#pragma unroll
  for (int j = 0; j < 12; ++j) {
    int d = l + 64 * j;
    float qkv = qk[(size_t)row * 768 + d];
    aS += qkv * g_in[d];
    aC += qkv * b_in[d] + q[(size_t)row * 768 + d] * bk[d];
  }
#pragma unroll
  for (int o = 32; o; o >>= 1) { aS += __shfl_xor(aS, o); aC += __shfl_xor(aC, o); }
  if (l == 0) { Sqbuf[row] = aS; c0buf[row] = aC; }
}

// ---------------- dots+softmax over packed-bf16 x; attn, w=a*r, rmu=r*mu ----------------
// grid (64 chunk, 32 b), 256 thr = 4 waves x 4 rows
__global__ void dots_k(const uint32* __restrict__ xh, const float* __restrict__ qk,
                       const float* __restrict__ g_in, const float* __restrict__ Sqbuf,
                       const float* __restrict__ c0buf, float* __restrict__ attnbuf,
                       float* __restrict__ wbuf, float* __restrict__ rmubuf) {
  __shared__ float qkgs[8][768];
  __shared__ float c0s[8], Sqs[8];
  int chunk = blockIdx.x, b = blockIdx.y, t = threadIdx.x, w = t >> 6, l = t & 63;
#pragma unroll
  for (int s2 = 0; s2 < 8; ++s2)
    for (int d = t; d < 768; d += 256)
      qkgs[s2][d] = qk[(size_t)b * 6144 + s2 * 768 + d] * g_in[d];
  if (t < 8) { c0s[t] = c0buf[b * 8 + t]; Sqs[t] = Sqbuf[b * 8 + t]; }
  __syncthreads();
  for (int rr = 0; rr < 4; ++rr) {
    int n = chunk * 16 + w * 4 + rr;
    size_t row = (size_t)b * 1024 + n;
    const uint32* xr = xh + row * 384;
    float va[6], vb[6], s = 0.f, ss = 0.f;
#pragma unroll
    for (int j = 0; j < 6; ++j) {
      uint32 u = xr[l + 64 * j];
      float a = __uint_as_float(u << 16);
      float bv = __uint_as_float(u & 0xffff0000u);
      va[j] = a; vb[j] = bv;
      s += a + bv; ss += a * a + bv * bv;
    }
#pragma unroll
    for (int o = 32; o; o >>= 1) { s += __shfl_xor(s, o); ss += __shfl_xor(ss, o); }
    float mu = s * (1.f / 768.f), r = rsqrtf(ss * (1.f / 768.f) - mu * mu + LNEPS);
    float rmu = r * mu;
    float sc[8];
    {  // slots 0..3
      float ds[4] = {};
#pragma unroll
      for (int j = 0; j < 6; ++j) {
        int d0 = 2 * (l + 64 * j);
#pragma unroll
        for (int s2 = 0; s2 < 4; ++s2) {
          float2 qg = *(const float2*)&qkgs[s2][d0];
          ds[s2] += qg.x * va[j] + qg.y * vb[j];
        }
      }
#pragma unroll
      for (int s2 = 0; s2 < 4; ++s2) {
#pragma unroll
        for (int o = 32; o; o >>= 1) ds[s2] += __shfl_xor(ds[s2], o);
        sc[s2] = (r * ds[s2] - rmu * Sqs[s2] + c0s[s2]) * SCALE_Q;
      }
    }
    {  // slots 4..7
      float ds[4] = {};
#pragma unroll
      for (int j = 0; j < 6; ++j) {
        int d0 = 2 * (l + 64 * j);
#pragma unroll
        for (int s2 = 0; s2 < 4; ++s2) {
          float2 qg = *(const float2*)&qkgs[s2 + 4][d0];
          ds[s2] += qg.x * va[j] + qg.y * vb[j];
        }
      }
#pragma unroll
      for (int s2 = 0; s2 < 4; ++s2) {
#pragma unroll
        for (int o = 32; o; o >>= 1) ds[s2] += __shfl_xor(ds[s2], o);
        sc[s2 + 4] = (r * ds[s2] - rmu * Sqs[s2 + 4] + c0s[s2 + 4]) * SCALE_Q;
      }
    }
    float mx = sc[0];
#pragma unroll
    for (int s2 = 1; s2 < 8; ++s2) mx = fmaxf(mx, sc[s2]);
    float e[8], se = 0.f;
#pragma unroll
    for (int s2 = 0; s2 < 8; ++s2) { e[s2] = __expf(sc[s2] - mx); se += e[s2]; }
    float inv_se = 1.f / se;
    float a = e[0];
#pragma unroll
    for (int s2 = 1; s2 < 8; ++s2) a = (l == s2) ? e[s2] : a;
    a *= inv_se;
    if (l < 8) {
      attnbuf[row * 8 + l] = a;
      wbuf[row * 8 + l] = a * r;
    }
    if (l == 8) rmubuf[row] = rmu;
  }
}

// ---------------- deterministic A0/A1 reduce: A0=sum a, A1=sum a*rmu ----------------
__global__ void A_reduce_k(const float* __restrict__ attnbuf, const float* __restrict__ rmubuf,
                           float* __restrict__ gA0, float* __restrict__ gA1) {
  __shared__ float r0s[256], r1s[256];
  int b = blockIdx.x, t = threadIdx.x;
  float a0 = 0.f, a1 = 0.f;
  for (int j = 0; j < 32; ++j) {
    float a = attnbuf[(size_t)b * 8192 + j * 256 + t];
    float rm = rmubuf[b * 1024 + j * 32 + (t >> 3)];
    a0 += a; a1 += a * rm;
  }
  r0s[t] = a0; r1s[t] = a1;
  __syncthreads();
  if (t < 8) {
    float s0 = 0.f, s1 = 0.f;
    for (int k = 0; k < 32; ++k) { s0 += r0s[t + 8 * k]; s1 += r1s[t + 8 * k]; }
    gA0[b * 8 + t] = s0; gA1[b * 8 + t] = s1;
  }
}

// ---------------- pool packed-bf16 x with weights w -> partials[chunk][b*8+s][768] -------
// grid (16 chunk, 32 b), 384 thr: thread owns packed col t (d=2t,2t+1)
__global__ void pool_k(const uint32* __restrict__ xh, const float* __restrict__ wbuf,
                       float* __restrict__ partials) {
  __shared__ float ws[64][8];
  int chunk = blockIdx.x, b = blockIdx.y, t = threadIdx.x;
  for (int i = t; i < 512; i += 384)
    ((float*)ws)[i] = wbuf[((size_t)b * 1024 + chunk * 64) * 8 + i];
  __syncthreads();
  float acc[8][2] = {};
  const uint32* xp = xh + ((size_t)b * 1024 + chunk * 64) * 384;
  for (int nn = 0; nn < 64; ++nn) {
    uint32 u = xp[(size_t)nn * 384 + t];
    float x0 = __uint_as_float(u << 16);
    float x1 = __uint_as_float(u & 0xffff0000u);
#pragma unroll
    for (int s2 = 0; s2 < 8; ++s2) {
      float wv = ws[nn][s2];
      acc[s2][0] += wv * x0; acc[s2][1] += wv * x1;
    }
  }
#pragma unroll
  for (int s2 = 0; s2 < 8; ++s2) {
    size_t base = ((size_t)(chunk * 256 + b * 8 + s2)) * 768;
    float2 v; v.x = acc[s2][0]; v.y = acc[s2][1];
    *(float2*)&partials[base + 2 * t] = v;
  }
}

// ---------------- reduce partials + LN-fixup -> pooled ; inv, rho ----------------
__global__ void reduce_fix_k(const float* __restrict__ partials, const float* __restrict__ gA0,
                             const float* __restrict__ gA1, const float* __restrict__ g_in,
                             const float* __restrict__ b_in, float* __restrict__ pooled,
                             float* __restrict__ invbuf, float* __restrict__ rhobuf) {
  int row = blockIdx.x, t = threadIdx.x;  // row = b*8+s
  float A0 = gA0[row], A1 = gA1[row];
#pragma unroll
  for (int c = 0; c < 3; ++c) {
    int d = t + 256 * c;
    float a = 0.f;
    for (int ch = 0; ch < 16; ++ch) a += partials[((size_t)(ch * 256 + row)) * 768 + d];
    pooled[(size_t)row * 768 + d] = g_in[d] * (a - A1) + b_in[d] * A0;
  }
  if (t == 0) {
    float iv = 1.f / (A0 + AEPS);
    invbuf[row] = iv;
    rhobuf[row] = A0 * iv;
  }
}

// ---------------- output writers (fp32) ----------------
__global__ void out_slots_k(const float* __restrict__ slots, float* __restrict__ out) {
  int i = blockIdx.x * 256 + threadIdx.x;  // 196608
  out[i] = slots[i];
}
__global__ void out_attn_k(const float* __restrict__ attnbuf, const float* __restrict__ invbuf,
                           float* __restrict__ out) {
  int i = blockIdx.x * 256 + threadIdx.x;  // 262144 ; layout [b][n][s]
  out[196608 + i] = attnbuf[i] * invbuf[((i >> 13) << 3) + (i & 7)];
}

extern "C" void kernel_launch(void* const* d_in, const int* in_sizes, int n_in,
                              void* d_out, int out_size, void* d_ws, size_t ws_size,
                              hipStream_t stream) {
  (void)in_sizes; (void)n_in; (void)out_size; (void)ws_size;
  const float* slots0 = (const float*)d_in[0];
  const float* inputs = (const float*)d_in[1];
  const float* Wq = (const float*)d_in[2];
  const float* bq = (const float*)d_in[3];
  const float* Wk = (const float*)d_in[4];
  const float* bk = (const float*)d_in[5];
  const float* Wv = (const float*)d_in[6];
  const float* bv = (const float*)d_in[7];
  const float* g_in = (const float*)d_in[8];
  const float* b_in = (const float*)d_in[9];
  const float* g_s = (const float*)d_in[10];
  const float* b_s = (const float*)d_in[11];
  const float* g_ff = (const float*)d_in[12];
  const float* b_ff = (const float*)d_in[13];
  const float* W1 = (const float*)d_in[14];
  const float* b1 = (const float*)d_in[15];
  const float* W2 = (const float*)d_in[16];
  const float* b2 = (const float*)d_in[17];

  char* p = (char*)d_ws;
  uint32* xh = (uint32*)p;     p += (size_t)32768 * 384 * 4;  // packed bf16 inputs
  float* WkT = (float*)p;      p += (size_t)768 * 768 * 4;
  float* slotsf = (float*)p;   p += 256 * 768 * 4;
  float* qbuf = (float*)p;     p += 256 * 768 * 4;
  float* qkbuf = (float*)p;    p += 256 * 768 * 4;
  float* Sqbuf = (float*)p;    p += 256 * 4;
  float* c0buf = (float*)p;    p += 256 * 4;
  float* attnbuf = (float*)p;  p += (size_t)32768 * 8 * 4;
  float* wbuf = (float*)p;     p += (size_t)32768 * 8 * 4;
  float* rmubuf = (float*)p;   p += 32768 * 4;
  float* partials = (float*)p; p += (size_t)16 * 256 * 768 * 4;
  float* gA0 = (float*)p;      p += 256 * 4;
  float* gA1 = (float*)p;      p += 256 * 4;
  float* pooled = (float*)p;   p += 256 * 768 * 4;
  float* invbuf = (float*)p;   p += 256 * 4;
  float* rhobuf = (float*)p;   p += 256 * 4;
  float* updbuf = (float*)p;   p += 256 * 768 * 4;
  float* t1buf = (float*)p;    p += 256 * 768 * 4;

  dim3 ggrid(12, 16);
  cast_k<<<24576, 256, 0, stream>>>(inputs, xh);
  packT_k<<<dim3(24, 24), 256, 0, stream>>>(Wk, WkT);
  init_slots_k<<<768, 256, 0, stream>>>(slots0, slotsf);
  for (int it = 0; it < 3; ++it) {
    gemv_k<true, 0><<<ggrid, 1024, 0, stream>>>(slotsf, Wq, bq, g_s, b_s, nullptr, nullptr, qbuf);
    gemv_k<false, 1><<<ggrid, 1024, 0, stream>>>(qbuf, WkT, nullptr, nullptr, nullptr, nullptr,
                                                 nullptr, qkbuf);
    qprep_k<<<64, 256, 0, stream>>>(qbuf, qkbuf, g_in, b_in, bk, Sqbuf, c0buf);
    dots_k<<<dim3(64, 32), 256, 0, stream>>>(xh, qkbuf, g_in, Sqbuf, c0buf, attnbuf, wbuf,
                                             rmubuf);
    A_reduce_k<<<32, 256, 0, stream>>>(attnbuf, rmubuf, gA0, gA1);
    pool_k<<<dim3(16, 32), 384, 0, stream>>>(xh, wbuf, partials);
    reduce_fix_k<<<256, 256, 0, stream>>>(partials, gA0, gA1, g_in, b_in, pooled, invbuf,
                                          rhobuf);
    gemv_k<false, 2><<<ggrid, 1024, 0, stream>>>(pooled, Wv, bv, nullptr, nullptr, invbuf,
                                                 rhobuf, updbuf);
    gemv_k<true, 3><<<ggrid, 1024, 0, stream>>>(updbuf, W1, b1, g_ff, b_ff, nullptr, nullptr,
                                                t1buf);
    gemv_k<false, 4><<<ggrid, 1024, 0, stream>>>(t1buf, W2, b2, nullptr, nullptr, nullptr,
                                                 nullptr, slotsf);
  }
  out_slots_k<<<768, 256, 0, stream>>>(slotsf, (float*)d_out);
  out_attn_k<<<1024, 256, 0, stream>>>(attnbuf, invbuf, (float*)d_out);
}

// Round 9
// 634.158 us; speedup vs baseline: 1.6793x; 1.1284x over previous
//
#include <hip/hip_runtime.h>

#define LNEPS 1e-5f
#define AEPS 1e-8f
#define SCALE_Q 0.036084391824351615f  // 768^-0.5

typedef unsigned int uint32;

__device__ inline unsigned short bfb(float f) {
  __bf16 h = (__bf16)f;
  unsigned short u;
  __builtin_memcpy(&u, &h, 2);
  return u;
}

// ---------------- one-time: cast inputs fp32 -> packed bf16 (uint = 2 elems) ----------------
__global__ void cast_k(const float* __restrict__ in, uint32* __restrict__ xh) {
  size_t i = (size_t)blockIdx.x * 256 + threadIdx.x;  // 6291456 float4s
  float4 v = ((const float4*)in)[i];
  uint2 o;
  o.x = (uint32)bfb(v.x) | ((uint32)bfb(v.y) << 16);
  o.y = (uint32)bfb(v.z) | ((uint32)bfb(v.w) << 16);
  ((uint2*)xh)[i] = o;
}

// ---------------- transpose 768x768 fp32: WT[c][i] = W[i][c] ----------------
__global__ void packT_k(const float* __restrict__ W, float* __restrict__ WT) {
  __shared__ float tile[32][33];
  int c0 = blockIdx.x * 32, i0 = blockIdx.y * 32;
  int tx = threadIdx.x & 31, ty = threadIdx.x >> 5;  // 32x8
#pragma unroll
  for (int k = 0; k < 4; ++k)
    tile[ty + 8 * k][tx] = W[(size_t)(i0 + ty + 8 * k) * 768 + c0 + tx];
  __syncthreads();
#pragma unroll
  for (int k = 0; k < 4; ++k)
    WT[(size_t)(c0 + ty + 8 * k) * 768 + i0 + tx] = tile[tx][ty + 8 * k];
}

// ---------------- broadcast slots to all batch rows ----------------
__global__ void init_slots_k(const float* __restrict__ s0, float* __restrict__ slots) {
  int idx = blockIdx.x * 256 + threadIdx.x;  // 196608
  slots[idx] = s0[idx % 6144];
}

// ---------------- generic batched GEMV, grid (24 colblk, 32 rowblk), 256 thr ----------------
// 8 rows x 32 cols per block; thread: cx=t&7 (4 cols), rw=(t>>3)&7, kg=t>>6 (192 k each).
// MODE 0: acc+bias | 1: acc | 2: alpha[r]*acc+beta[r]*bias | 3: relu(acc+bias) | 4: out+=acc+bias
template <bool LN, int MODE>
__global__ void gemv_k(const float* __restrict__ X, const float* __restrict__ W,
                       const float* __restrict__ bias, const float* __restrict__ gamma,
                       const float* __restrict__ beta_ln, const float* __restrict__ alpha,
                       const float* __restrict__ beta, float* __restrict__ out) {
  __shared__ float Xs[8][772];
  __shared__ float sm[8], sr[8];
  int c0 = blockIdx.x * 32, r0 = blockIdx.y * 8, t = threadIdx.x;
#pragma unroll
  for (int j = 0; j < 6; ++j) {
    int fidx = j * 256 + t;  // 1536 float4s
    int r = fidx / 192, c4 = fidx % 192;
    *(float4*)&Xs[r][c4 * 4] = *(const float4*)(X + (size_t)(r0 + r) * 768 + c4 * 4);
  }
  __syncthreads();
  if (LN) {
    int w = t >> 6, l = t & 63;
#pragma unroll
    for (int jr = 0; jr < 2; ++jr) {
      int r = w + 4 * jr;
      float s = 0.f, ss = 0.f;
#pragma unroll
      for (int m2 = 0; m2 < 12; ++m2) { float x = Xs[r][l + 64 * m2]; s += x; ss += x * x; }
#pragma unroll
      for (int o = 32; o; o >>= 1) { s += __shfl_xor(s, o); ss += __shfl_xor(ss, o); }
      if (l == 0) {
        float mu = s * (1.f / 768.f);
        sm[r] = mu;
        sr[r] = rsqrtf(ss * (1.f / 768.f) - mu * mu + LNEPS);
      }
    }
    __syncthreads();
#pragma unroll
    for (int j = 0; j < 24; ++j) {
      int idx = j * 256 + t;  // 6144
      int r = idx / 768, d = idx % 768;
      Xs[r][d] = (Xs[r][d] - sm[r]) * sr[r] * gamma[d] + beta_ln[d];
    }
    __syncthreads();
  }
  int cx = t & 7, rw = (t >> 3) & 7, kg = t >> 6;
  int c = c0 + cx * 4;
  float ax = 0.f, ay = 0.f, az = 0.f, aw = 0.f;
  const float* wp = W + c;
  int k0 = kg * 192;
  for (int k = k0; k < k0 + 192; k += 4) {
#pragma unroll
    for (int kk = 0; kk < 4; ++kk) {
      float4 wv = *(const float4*)(wp + (size_t)(k + kk) * 768);
      float xv = Xs[rw][k + kk];
      ax += xv * wv.x; ay += xv * wv.y; az += xv * wv.z; aw += xv * wv.w;
    }
  }
  __syncthreads();  // all kg done reading Xs; reuse as reduce buffer
  float* red = (float*)Xs;
  if (kg > 0) {
    float4 v; v.x = ax; v.y = ay; v.z = az; v.w = aw;
    *(float4*)&red[(size_t)(((kg - 1) * 64 + rw * 8 + cx)) * 4] = v;
  }
  __syncthreads();
  if (kg == 0) {
#pragma unroll
    for (int g = 1; g < 4; ++g) {
      float4 v = *(const float4*)&red[(size_t)(((g - 1) * 64 + rw * 8 + cx)) * 4];
      ax += v.x; ay += v.y; az += v.z; aw += v.w;
    }
    int rr = r0 + rw;
    size_t oidx = (size_t)rr * 768 + c;
    float4 res;
    if (MODE == 0) {
      float4 b4 = *(const float4*)(bias + c);
      res.x = ax + b4.x; res.y = ay + b4.y; res.z = az + b4.z; res.w = aw + b4.w;
    } else if (MODE == 1) {
      res.x = ax; res.y = ay; res.z = az; res.w = aw;
    } else if (MODE == 2) {
      float4 b4 = *(const float4*)(bias + c);
      float al = alpha[rr], be = beta[rr];
      res.x = ax * al + b4.x * be; res.y = ay * al + b4.y * be;
      res.z = az * al + b4.z * be; res.w = aw * al + b4.w * be;
    } else if (MODE == 3) {
      float4 b4 = *(const float4*)(bias + c);
      res.x = fmaxf(ax + b4.x, 0.f); res.y = fmaxf(ay + b4.y, 0.f);
      res.z = fmaxf(az + b4.z, 0.f); res.w = fmaxf(aw + b4.w, 0.f);
    } else {
      float4 b4 = *(const float4*)(bias + c);
      float4 old = *(const float4*)(out + oidx);
      res.x = old.x + ax + b4.x; res.y = old.y + ay + b4.y;
      res.z = old.z + az + b4.z; res.w = old.w + aw + b4.w;
    }
    *(float4*)(out + oidx) = res;
  }
}

// ---------------- per-slot scalars: Sq = qk.g_in ; c0 = qk.b_in + q.bk ----------------
__global__ void qprep_k(const float* __restrict__ q, const float* __restrict__ qk,
                        const float* __restrict__ g_in, const float* __restrict__ b_in,
                        const float* __restrict__ bk, float* __restrict__ Sqbuf,
                        float* __restrict__ c0buf) {
  int row = blockIdx.x * 4 + (threadIdx.x >> 6), l = threadIdx.x & 63;
  float aS = 0.f, aC = 0.f;
#pragma unroll
  for (int j = 0; j < 12; ++j) {
    int d = l + 64 * j;
    float qkv = qk[(size_t)row * 768 + d];
    aS += qkv * g_in[d];
    aC += qkv * b_in[d] + q[(size_t)row * 768 + d] * bk[d];
  }
#pragma unroll
  for (int o = 32; o; o >>= 1) { aS += __shfl_xor(aS, o); aC += __shfl_xor(aC, o); }
  if (l == 0) { Sqbuf[row] = aS; c0buf[row] = aC; }
}

// ---------------- dots+softmax over packed-bf16 x; attn, w=a*r, rmu=r*mu ----------------
// grid (64 chunk, 32 b), 256 thr = 4 waves x 4 rows; VGPR cap 128 (4 blocks/CU)
__global__ void __launch_bounds__(256, 4)
dots_k(const uint32* __restrict__ xh, const float* __restrict__ qk,
       const float* __restrict__ g_in, const float* __restrict__ Sqbuf,
       const float* __restrict__ c0buf, float* __restrict__ attnbuf,
       float* __restrict__ wbuf, float* __restrict__ rmubuf) {
  __shared__ float qkgs[8][768];
  __shared__ float c0s[8], Sqs[8];
  int chunk = blockIdx.x, b = blockIdx.y, t = threadIdx.x, w = t >> 6, l = t & 63;
#pragma unroll
  for (int s2 = 0; s2 < 8; ++s2)
    for (int d = t; d < 768; d += 256)
      qkgs[s2][d] = qk[(size_t)b * 6144 + s2 * 768 + d] * g_in[d];
  if (t < 8) { c0s[t] = c0buf[b * 8 + t]; Sqs[t] = Sqbuf[b * 8 + t]; }
  __syncthreads();
  for (int rr = 0; rr < 4; ++rr) {
    int n = chunk * 16 + w * 4 + rr;
    size_t row = (size_t)b * 1024 + n;
    const uint32* xr = xh + row * 384;
    float va[6], vb[6], s = 0.f, ss = 0.f;
#pragma unroll
    for (int j = 0; j < 6; ++j) {
      uint32 u = xr[l + 64 * j];
      float a = __uint_as_float(u << 16);
      float bv = __uint_as_float(u & 0xffff0000u);
      va[j] = a; vb[j] = bv;
      s += a + bv; ss += a * a + bv * bv;
    }
#pragma unroll
    for (int o = 32; o; o >>= 1) { s += __shfl_xor(s, o); ss += __shfl_xor(ss, o); }
    float mu = s * (1.f / 768.f), r = rsqrtf(ss * (1.f / 768.f) - mu * mu + LNEPS);
    float rmu = r * mu;
    float ds[8] = {};
#pragma unroll
    for (int j = 0; j < 6; ++j) {
      int d0 = 2 * (l + 64 * j);
#pragma unroll
      for (int s2 = 0; s2 < 8; ++s2) {
        float2 qg = *(const float2*)&qkgs[s2][d0];
        ds[s2] += qg.x * va[j] + qg.y * vb[j];
      }
    }
    float sc[8];
#pragma unroll
    for (int s2 = 0; s2 < 8; ++s2) {
#pragma unroll
      for (int o = 32; o; o >>= 1) ds[s2] += __shfl_xor(ds[s2], o);
      sc[s2] = (r * ds[s2] - rmu * Sqs[s2] + c0s[s2]) * SCALE_Q;
    }
    float mx = sc[0];
#pragma unroll
    for (int s2 = 1; s2 < 8; ++s2) mx = fmaxf(mx, sc[s2]);
    float e[8], se = 0.f;
#pragma unroll
    for (int s2 = 0; s2 < 8; ++s2) { e[s2] = __expf(sc[s2] - mx); se += e[s2]; }
    float inv_se = 1.f / se;
    float a = e[0];
#pragma unroll
    for (int s2 = 1; s2 < 8; ++s2) a = (l == s2) ? e[s2] : a;
    a *= inv_se;
    if (l < 8) {
      attnbuf[row * 8 + l] = a;
      wbuf[row * 8 + l] = a * r;
    }
    if (l == 8) rmubuf[row] = rmu;
  }
}

// ---------------- pool packed-bf16 x with weights w -> partials[chunk][b*8+s][768] -------
// grid (16 chunk, 32 b), 384 thr: thread owns packed col t (d=2t,2t+1)
__global__ void pool_k(const uint32* __restrict__ xh, const float* __restrict__ wbuf,
                       float* __restrict__ partials) {
  __shared__ float ws[64][8];
  int chunk = blockIdx.x, b = blockIdx.y, t = threadIdx.x;
  for (int i = t; i < 512; i += 384)
    ((float*)ws)[i] = wbuf[((size_t)b * 1024 + chunk * 64) * 8 + i];
  __syncthreads();
  float acc[8][2] = {};
  const uint32* xp = xh + ((size_t)b * 1024 + chunk * 64) * 384;
  for (int nn = 0; nn < 64; ++nn) {
    uint32 u = xp[(size_t)nn * 384 + t];
    float x0 = __uint_as_float(u << 16);
    float x1 = __uint_as_float(u & 0xffff0000u);
#pragma unroll
    for (int s2 = 0; s2 < 8; ++s2) {
      float wv = ws[nn][s2];
      acc[s2][0] += wv * x0; acc[s2][1] += wv * x1;
    }
  }
#pragma unroll
  for (int s2 = 0; s2 < 8; ++s2) {
    size_t base = ((size_t)(chunk * 256 + b * 8 + s2)) * 768;
    float2 v; v.x = acc[s2][0]; v.y = acc[s2][1];
    *(float2*)&partials[base + 2 * t] = v;
  }
}

// ---------------- reduce partials + A0/A1 + LN-fixup -> pooled ; inv, rho ----------------
// grid 256 (row = b*8+s), 256 thr
__global__ void reduce_fix_k(const float* __restrict__ partials, const float* __restrict__ attnbuf,
                             const float* __restrict__ rmubuf, const float* __restrict__ g_in,
                             const float* __restrict__ b_in, float* __restrict__ pooled,
                             float* __restrict__ invbuf, float* __restrict__ rhobuf) {
  __shared__ float rA[4], rB[4], sAB[2];
  int row = blockIdx.x, t = threadIdx.x;  // row = b*8+s
  int b = row >> 3, sl = row & 7;
  float a0 = 0.f, a1 = 0.f;
#pragma unroll
  for (int j = 0; j < 4; ++j) {
    int n = t + 256 * j;
    float a = attnbuf[((size_t)b * 1024 + n) * 8 + sl];
    a0 += a;
    a1 += a * rmubuf[b * 1024 + n];
  }
#pragma unroll
  for (int o = 32; o; o >>= 1) { a0 += __shfl_xor(a0, o); a1 += __shfl_xor(a1, o); }
  if ((t & 63) == 0) { rA[t >> 6] = a0; rB[t >> 6] = a1; }
  __syncthreads();
  if (t == 0) {
    sAB[0] = rA[0] + rA[1] + rA[2] + rA[3];
    sAB[1] = rB[0] + rB[1] + rB[2] + rB[3];
  }
  __syncthreads();
  float A0 = sAB[0], A1 = sAB[1];
#pragma unroll
  for (int c = 0; c < 3; ++c) {
    int d = t + 256 * c;
    float a = 0.f;
    for (int ch = 0; ch < 16; ++ch) a += partials[((size_t)(ch * 256 + row)) * 768 + d];
    pooled[(size_t)row * 768 + d] = g_in[d] * (a - A1) + b_in[d] * A0;
  }
  if (t == 0) {
    float iv = 1.f / (A0 + AEPS);
    invbuf[row] = iv;
    rhobuf[row] = A0 * iv;
  }
}

// ---------------- output writers (fp32) ----------------
__global__ void out_slots_k(const float* __restrict__ slots, float* __restrict__ out) {
  int i = blockIdx.x * 256 + threadIdx.x;  // 196608
  out[i] = slots[i];
}
__global__ void out_attn_k(const float* __restrict__ attnbuf, const float* __restrict__ invbuf,
                           float* __restrict__ out) {
  int i = blockIdx.x * 256 + threadIdx.x;  // 262144 ; layout [b][n][s]
  out[196608 + i] = attnbuf[i] * invbuf[((i >> 13) << 3) + (i & 7)];
}

extern "C" void kernel_launch(void* const* d_in, const int* in_sizes, int n_in,
                              void* d_out, int out_size, void* d_ws, size_t ws_size,
                              hipStream_t stream) {
  (void)in_sizes; (void)n_in; (void)out_size; (void)ws_size;
  const float* slots0 = (const float*)d_in[0];
  const float* inputs = (const float*)d_in[1];
  const float* Wq = (const float*)d_in[2];
  const float* bq = (const float*)d_in[3];
  const float* Wk = (const float*)d_in[4];
  const float* bk = (const float*)d_in[5];
  const float* Wv = (const float*)d_in[6];
  const float* bv = (const float*)d_in[7];
  const float* g_in = (const float*)d_in[8];
  const float* b_in = (const float*)d_in[9];
  const float* g_s = (const float*)d_in[10];
  const float* b_s = (const float*)d_in[11];
  const float* g_ff = (const float*)d_in[12];
  const float* b_ff = (const float*)d_in[13];
  const float* W1 = (const float*)d_in[14];
  const float* b1 = (const float*)d_in[15];
  const float* W2 = (const float*)d_in[16];
  const float* b2 = (const float*)d_in[17];

  char* p = (char*)d_ws;
  uint32* xh = (uint32*)p;     p += (size_t)32768 * 384 * 4;  // packed bf16 inputs
  float* WkT = (float*)p;      p += (size_t)768 * 768 * 4;
  float* slotsf = (float*)p;   p += 256 * 768 * 4;
  float* qbuf = (float*)p;     p += 256 * 768 * 4;
  float* qkbuf = (float*)p;    p += 256 * 768 * 4;
  float* Sqbuf = (float*)p;    p += 256 * 4;
  float* c0buf = (float*)p;    p += 256 * 4;
  float* attnbuf = (float*)p;  p += (size_t)32768 * 8 * 4;
  float* wbuf = (float*)p;     p += (size_t)32768 * 8 * 4;
  float* rmubuf = (float*)p;   p += 32768 * 4;
  float* partials = (float*)p; p += (size_t)16 * 256 * 768 * 4;
  float* pooled = (float*)p;   p += 256 * 768 * 4;
  float* invbuf = (float*)p;   p += 256 * 4;
  float* rhobuf = (float*)p;   p += 256 * 4;
  float* updbuf = (float*)p;   p += 256 * 768 * 4;
  float* t1buf = (float*)p;    p += 256 * 768 * 4;

  dim3 ggrid(24, 32);
  cast_k<<<24576, 256, 0, stream>>>(inputs, xh);
  packT_k<<<dim3(24, 24), 256, 0, stream>>>(Wk, WkT);
  init_slots_k<<<768, 256, 0, stream>>>(slots0, slotsf);
  for (int it = 0; it < 3; ++it) {
    gemv_k<true, 0><<<ggrid, 256, 0, stream>>>(slotsf, Wq, bq, g_s, b_s, nullptr, nullptr, qbuf);
    gemv_k<false, 1><<<ggrid, 256, 0, stream>>>(qbuf, WkT, nullptr, nullptr, nullptr, nullptr,
                                                nullptr, qkbuf);
    qprep_k<<<64, 256, 0, stream>>>(qbuf, qkbuf, g_in, b_in, bk, Sqbuf, c0buf);
    dots_k<<<dim3(64, 32), 256, 0, stream>>>(xh, qkbuf, g_in, Sqbuf, c0buf, attnbuf, wbuf,
                                             rmubuf);
    pool_k<<<dim3(16, 32), 384, 0, stream>>>(xh, wbuf, partials);
    reduce_fix_k<<<256, 256, 0, stream>>>(partials, attnbuf, rmubuf, g_in, b_in, pooled,
                                          invbuf, rhobuf);
    gemv_k<false, 2><<<ggrid, 256, 0, stream>>>(pooled, Wv, bv, nullptr, nullptr, invbuf,
                                                rhobuf, updbuf);
    gemv_k<true, 3><<<ggrid, 256, 0, stream>>>(updbuf, W1, b1, g_ff, b_ff, nullptr, nullptr,
                                               t1buf);
    gemv_k<false, 4><<<ggrid, 256, 0, stream>>>(t1buf, W2, b2, nullptr, nullptr, nullptr,
                                                nullptr, slotsf);
  }
  out_slots_k<<<768, 256, 0, stream>>>(slotsf, (float*)d_out);
  out_attn_k<<<1024, 256, 0, stream>>>(attnbuf, invbuf, (float*)d_out);
}

// Round 10
// 606.532 us; speedup vs baseline: 1.7558x; 1.0455x over previous
//
#include <hip/hip_runtime.h>

#define LNEPS 1e-5f
#define AEPS 1e-8f
#define SCALE_Q 0.036084391824351615f  // 768^-0.5

typedef unsigned int uint32;

__device__ inline unsigned short bfb(float f) {
  __bf16 h = (__bf16)f;
  unsigned short u;
  __builtin_memcpy(&u, &h, 2);
  return u;
}

// ---------------- one-time: cast inputs fp32 -> packed bf16 (uint = 2 elems) ----------------
__global__ void cast_k(const float* __restrict__ in, uint32* __restrict__ xh) {
  size_t i = (size_t)blockIdx.x * 256 + threadIdx.x;  // 6291456 float4s
  float4 v = ((const float4*)in)[i];
  uint2 o;
  o.x = (uint32)bfb(v.x) | ((uint32)bfb(v.y) << 16);
  o.y = (uint32)bfb(v.z) | ((uint32)bfb(v.w) << 16);
  ((uint2*)xh)[i] = o;
}

// ---------------- transpose 768x768 fp32: WT[c][i] = W[i][c] ----------------
__global__ void packT_k(const float* __restrict__ W, float* __restrict__ WT) {
  __shared__ float tile[32][33];
  int c0 = blockIdx.x * 32, i0 = blockIdx.y * 32;
  int tx = threadIdx.x & 31, ty = threadIdx.x >> 5;  // 32x8
#pragma unroll
  for (int k = 0; k < 4; ++k)
    tile[ty + 8 * k][tx] = W[(size_t)(i0 + ty + 8 * k) * 768 + c0 + tx];
  __syncthreads();
#pragma unroll
  for (int k = 0; k < 4; ++k)
    WT[(size_t)(c0 + ty + 8 * k) * 768 + i0 + tx] = tile[tx][ty + 8 * k];
}

// ---------------- broadcast slots to all batch rows ----------------
__global__ void init_slots_k(const float* __restrict__ s0, float* __restrict__ slots) {
  int idx = blockIdx.x * 256 + threadIdx.x;  // 196608
  slots[idx] = s0[idx % 6144];
}

// ---------------- generic batched GEMV, grid (24 colblk, 32 rowblk), 256 thr ----------------
// 8 rows x 32 cols per block; thread: cx=t&7 (4 cols), rw=(t>>3)&7, kg=t>>6 (192 k each).
// MODE 0: acc+bias | 1: acc | 2: alpha[r]*acc+beta[r]*bias | 3: relu(acc+bias) | 4: out+=acc+bias
template <bool LN, int MODE>
__global__ void gemv_k(const float* __restrict__ X, const float* __restrict__ W,
                       const float* __restrict__ bias, const float* __restrict__ gamma,
                       const float* __restrict__ beta_ln, const float* __restrict__ alpha,
                       const float* __restrict__ beta, float* __restrict__ out) {
  __shared__ float Xs[8][772];
  __shared__ float sm[8], sr[8];
  int c0 = blockIdx.x * 32, r0 = blockIdx.y * 8, t = threadIdx.x;
#pragma unroll
  for (int j = 0; j < 6; ++j) {
    int fidx = j * 256 + t;  // 1536 float4s
    int r = fidx / 192, c4 = fidx % 192;
    *(float4*)&Xs[r][c4 * 4] = *(const float4*)(X + (size_t)(r0 + r) * 768 + c4 * 4);
  }
  __syncthreads();
  if (LN) {
    int w = t >> 6, l = t & 63;
#pragma unroll
    for (int jr = 0; jr < 2; ++jr) {
      int r = w + 4 * jr;
      float s = 0.f, ss = 0.f;
#pragma unroll
      for (int m2 = 0; m2 < 12; ++m2) { float x = Xs[r][l + 64 * m2]; s += x; ss += x * x; }
#pragma unroll
      for (int o = 32; o; o >>= 1) { s += __shfl_xor(s, o); ss += __shfl_xor(ss, o); }
      if (l == 0) {
        float mu = s * (1.f / 768.f);
        sm[r] = mu;
        sr[r] = rsqrtf(ss * (1.f / 768.f) - mu * mu + LNEPS);
      }
    }
    __syncthreads();
#pragma unroll
    for (int j = 0; j < 24; ++j) {
      int idx = j * 256 + t;  // 6144
      int r = idx / 768, d = idx % 768;
      Xs[r][d] = (Xs[r][d] - sm[r]) * sr[r] * gamma[d] + beta_ln[d];
    }
    __syncthreads();
  }
  int cx = t & 7, rw = (t >> 3) & 7, kg = t >> 6;
  int c = c0 + cx * 4;
  float ax = 0.f, ay = 0.f, az = 0.f, aw = 0.f;
  const float* wp = W + c;
  int k0 = kg * 192;
  for (int k = k0; k < k0 + 192; k += 4) {
#pragma unroll
    for (int kk = 0; kk < 4; ++kk) {
      float4 wv = *(const float4*)(wp + (size_t)(k + kk) * 768);
      float xv = Xs[rw][k + kk];
      ax += xv * wv.x; ay += xv * wv.y; az += xv * wv.z; aw += xv * wv.w;
    }
  }
  __syncthreads();  // all kg done reading Xs; reuse as reduce buffer
  float* red = (float*)Xs;
  if (kg > 0) {
    float4 v; v.x = ax; v.y = ay; v.z = az; v.w = aw;
    *(float4*)&red[(size_t)(((kg - 1) * 64 + rw * 8 + cx)) * 4] = v;
  }
  __syncthreads();
  if (kg == 0) {
#pragma unroll
    for (int g = 1; g < 4; ++g) {
      float4 v = *(const float4*)&red[(size_t)(((g - 1) * 64 + rw * 8 + cx)) * 4];
      ax += v.x; ay += v.y; az += v.z; aw += v.w;
    }
    int rr = r0 + rw;
    size_t oidx = (size_t)rr * 768 + c;
    float4 res;
    if (MODE == 0) {
      float4 b4 = *(const float4*)(bias + c);
      res.x = ax + b4.x; res.y = ay + b4.y; res.z = az + b4.z; res.w = aw + b4.w;
    } else if (MODE == 1) {
      res.x = ax; res.y = ay; res.z = az; res.w = aw;
    } else if (MODE == 2) {
      float4 b4 = *(const float4*)(bias + c);
      float al = alpha[rr], be = beta[rr];
      res.x = ax * al + b4.x * be; res.y = ay * al + b4.y * be;
      res.z = az * al + b4.z * be; res.w = aw * al + b4.w * be;
    } else if (MODE == 3) {
      float4 b4 = *(const float4*)(bias + c);
      res.x = fmaxf(ax + b4.x, 0.f); res.y = fmaxf(ay + b4.y, 0.f);
      res.z = fmaxf(az + b4.z, 0.f); res.w = fmaxf(aw + b4.w, 0.f);
    } else {
      float4 b4 = *(const float4*)(bias + c);
      float4 old = *(const float4*)(out + oidx);
      res.x = old.x + ax + b4.x; res.y = old.y + ay + b4.y;
      res.z = old.z + az + b4.z; res.w = old.w + aw + b4.w;
    }
    *(float4*)(out + oidx) = res;
  }
}

// ---------------- per-slot scalars: Sq = qk.g_in ; c0 = qk.b_in + q.bk ----------------
__global__ void qprep_k(const float* __restrict__ q, const float* __restrict__ qk,
                        const float* __restrict__ g_in, const float* __restrict__ b_in,
                        const float* __restrict__ bk, float* __restrict__ Sqbuf,
                        float* __restrict__ c0buf) {
  int row = blockIdx.x * 4 + (threadIdx.x >> 6), l = threadIdx.x & 63;
  float aS = 0.f, aC = 0.f;
#pragma unroll
  for (int j = 0; j < 12; ++j) {
    int d = l + 64 * j;
    float qkv = qk[(size_t)row * 768 + d];
    aS += qkv * g_in[d];
    aC += qkv * b_in[d] + q[(size_t)row * 768 + d] * bk[d];
  }
#pragma unroll
  for (int o = 32; o; o >>= 1) { aS += __shfl_xor(aS, o); aC += __shfl_xor(aC, o); }
  if (l == 0) { Sqbuf[row] = aS; c0buf[row] = aC; }
}

// ---------------- dots+softmax over packed-bf16 x; attn, w=a*r, rmu=r*mu ----------------
// grid (64 chunk, 32 b), 256 thr = 4 waves x 4 rows.
// Single fused j-loop: s, ss, ds[8] accumulate raw-x directly (LN-commute) -> no row cache.
__global__ void dots_k(const uint32* __restrict__ xh, const float* __restrict__ qk,
                       const float* __restrict__ g_in, const float* __restrict__ Sqbuf,
                       const float* __restrict__ c0buf, float* __restrict__ attnbuf,
                       float* __restrict__ wbuf, float* __restrict__ rmubuf) {
  __shared__ float qkgs[8][768];
  __shared__ float c0s[8], Sqs[8];
  int chunk = blockIdx.x, b = blockIdx.y, t = threadIdx.x, w = t >> 6, l = t & 63;
#pragma unroll
  for (int s2 = 0; s2 < 8; ++s2)
    for (int d = t; d < 768; d += 256)
      qkgs[s2][d] = qk[(size_t)b * 6144 + s2 * 768 + d] * g_in[d];
  if (t < 8) { c0s[t] = c0buf[b * 8 + t]; Sqs[t] = Sqbuf[b * 8 + t]; }
  __syncthreads();
  for (int rr = 0; rr < 4; ++rr) {
    int n = chunk * 16 + w * 4 + rr;
    size_t row = (size_t)b * 1024 + n;
    const uint32* xr = xh + row * 384;
    float s = 0.f, ss = 0.f, ds[8] = {};
#pragma unroll
    for (int j = 0; j < 6; ++j) {
      uint32 u = xr[l + 64 * j];
      float a = __uint_as_float(u << 16);
      float bv = __uint_as_float(u & 0xffff0000u);
      s += a + bv;
      ss += a * a + bv * bv;
      int d0 = 2 * (l + 64 * j);
#pragma unroll
      for (int s2 = 0; s2 < 8; ++s2) {
        float2 qg = *(const float2*)&qkgs[s2][d0];
        ds[s2] += qg.x * a + qg.y * bv;
      }
    }
#pragma unroll
    for (int o = 32; o; o >>= 1) {
      s += __shfl_xor(s, o);
      ss += __shfl_xor(ss, o);
#pragma unroll
      for (int s2 = 0; s2 < 8; ++s2) ds[s2] += __shfl_xor(ds[s2], o);
    }
    float mu = s * (1.f / 768.f), r = rsqrtf(ss * (1.f / 768.f) - mu * mu + LNEPS);
    float rmu = r * mu;
    float sc[8];
#pragma unroll
    for (int s2 = 0; s2 < 8; ++s2)
      sc[s2] = (r * ds[s2] - rmu * Sqs[s2] + c0s[s2]) * SCALE_Q;
    float mx = sc[0];
#pragma unroll
    for (int s2 = 1; s2 < 8; ++s2) mx = fmaxf(mx, sc[s2]);
    float e[8], se = 0.f;
#pragma unroll
    for (int s2 = 0; s2 < 8; ++s2) { e[s2] = __expf(sc[s2] - mx); se += e[s2]; }
    float inv_se = 1.f / se;
    float a = e[0];
#pragma unroll
    for (int s2 = 1; s2 < 8; ++s2) a = (l == s2) ? e[s2] : a;
    a *= inv_se;
    if (l < 8) {
      attnbuf[row * 8 + l] = a;
      wbuf[row * 8 + l] = a * r;
    }
    if (l == 8) rmubuf[row] = rmu;
  }
}

// ---------------- pool packed-bf16 x with weights w -> partials[chunk][b*8+s][768] -------
// grid (16 chunk, 32 b), 384 thr: thread owns packed col t (d=2t,2t+1)
__global__ void pool_k(const uint32* __restrict__ xh, const float* __restrict__ wbuf,
                       float* __restrict__ partials) {
  __shared__ float ws[64][8];
  int chunk = blockIdx.x, b = blockIdx.y, t = threadIdx.x;
  for (int i = t; i < 512; i += 384)
    ((float*)ws)[i] = wbuf[((size_t)b * 1024 + chunk * 64) * 8 + i];
  __syncthreads();
  float acc[8][2] = {};
  const uint32* xp = xh + ((size_t)b * 1024 + chunk * 64) * 384;
  for (int nn = 0; nn < 64; ++nn) {
    uint32 u = xp[(size_t)nn * 384 + t];
    float x0 = __uint_as_float(u << 16);
    float x1 = __uint_as_float(u & 0xffff0000u);
#pragma unroll
    for (int s2 = 0; s2 < 8; ++s2) {
      float wv = ws[nn][s2];
      acc[s2][0] += wv * x0; acc[s2][1] += wv * x1;
    }
  }
#pragma unroll
  for (int s2 = 0; s2 < 8; ++s2) {
    size_t base = ((size_t)(chunk * 256 + b * 8 + s2)) * 768;
    float2 v; v.x = acc[s2][0]; v.y = acc[s2][1];
    *(float2*)&partials[base + 2 * t] = v;
  }
}

// ---------------- reduce partials + A0/A1 + LN-fixup -> pooled ; inv, rho ----------------
// grid 256 (row = b*8+s), 256 thr
__global__ void reduce_fix_k(const float* __restrict__ partials, const float* __restrict__ attnbuf,
                             const float* __restrict__ rmubuf, const float* __restrict__ g_in,
                             const float* __restrict__ b_in, float* __restrict__ pooled,
                             float* __restrict__ invbuf, float* __restrict__ rhobuf) {
  __shared__ float rA[4], rB[4], sAB[2];
  int row = blockIdx.x, t = threadIdx.x;  // row = b*8+s
  int b = row >> 3, sl = row & 7;
  float a0 = 0.f, a1 = 0.f;
#pragma unroll
  for (int j = 0; j < 4; ++j) {
    int n = t + 256 * j;
    float a = attnbuf[((size_t)b * 1024 + n) * 8 + sl];
    a0 += a;
    a1 += a * rmubuf[b * 1024 + n];
  }
#pragma unroll
  for (int o = 32; o; o >>= 1) { a0 += __shfl_xor(a0, o); a1 += __shfl_xor(a1, o); }
  if ((t & 63) == 0) { rA[t >> 6] = a0; rB[t >> 6] = a1; }
  __syncthreads();
  if (t == 0) {
    sAB[0] = rA[0] + rA[1] + rA[2] + rA[3];
    sAB[1] = rB[0] + rB[1] + rB[2] + rB[3];
  }
  __syncthreads();
  float A0 = sAB[0], A1 = sAB[1];
#pragma unroll
  for (int c = 0; c < 3; ++c) {
    int d = t + 256 * c;
    float a = 0.f;
    for (int ch = 0; ch < 16; ++ch) a += partials[((size_t)(ch * 256 + row)) * 768 + d];
    pooled[(size_t)row * 768 + d] = g_in[d] * (a - A1) + b_in[d] * A0;
  }
  if (t == 0) {
    float iv = 1.f / (A0 + AEPS);
    invbuf[row] = iv;
    rhobuf[row] = A0 * iv;
  }
}

// ---------------- output writers (fp32) ----------------
__global__ void out_slots_k(const float* __restrict__ slots, float* __restrict__ out) {
  int i = blockIdx.x * 256 + threadIdx.x;  // 196608
  out[i] = slots[i];
}
__global__ void out_attn_k(const float* __restrict__ attnbuf, const float* __restrict__ invbuf,
                           float* __restrict__ out) {
  int i = blockIdx.x * 256 + threadIdx.x;  // 262144 ; layout [b][n][s]
  out[196608 + i] = attnbuf[i] * invbuf[((i >> 13) << 3) + (i & 7)];
}

extern "C" void kernel_launch(void* const* d_in, const int* in_sizes, int n_in,
                              void* d_out, int out_size, void* d_ws, size_t ws_size,
                              hipStream_t stream) {
  (void)in_sizes; (void)n_in; (void)out_size; (void)ws_size;
  const float* slots0 = (const float*)d_in[0];
  const float* inputs = (const float*)d_in[1];
  const float* Wq = (const float*)d_in[2];
  const float* bq = (const float*)d_in[3];
  const float* Wk = (const float*)d_in[4];
  const float* bk = (const float*)d_in[5];
  const float* Wv = (const float*)d_in[6];
  const float* bv = (const float*)d_in[7];
  const float* g_in = (const float*)d_in[8];
  const float* b_in = (const float*)d_in[9];
  const float* g_s = (const float*)d_in[10];
  const float* b_s = (const float*)d_in[11];
  const float* g_ff = (const float*)d_in[12];
  const float* b_ff = (const float*)d_in[13];
  const float* W1 = (const float*)d_in[14];
  const float* b1 = (const float*)d_in[15];
  const float* W2 = (const float*)d_in[16];
  const float* b2 = (const float*)d_in[17];

  char* p = (char*)d_ws;
  uint32* xh = (uint32*)p;     p += (size_t)32768 * 384 * 4;  // packed bf16 inputs
  float* WkT = (float*)p;      p += (size_t)768 * 768 * 4;
  float* slotsf = (float*)p;   p += 256 * 768 * 4;
  float* qbuf = (float*)p;     p += 256 * 768 * 4;
  float* qkbuf = (float*)p;    p += 256 * 768 * 4;
  float* Sqbuf = (float*)p;    p += 256 * 4;
  float* c0buf = (float*)p;    p += 256 * 4;
  float* attnbuf = (float*)p;  p += (size_t)32768 * 8 * 4;
  float* wbuf = (float*)p;     p += (size_t)32768 * 8 * 4;
  float* rmubuf = (float*)p;   p += 32768 * 4;
  float* partials = (float*)p; p += (size_t)16 * 256 * 768 * 4;
  float* pooled = (float*)p;   p += 256 * 768 * 4;
  float* invbuf = (float*)p;   p += 256 * 4;
  float* rhobuf = (float*)p;   p += 256 * 4;
  float* updbuf = (float*)p;   p += 256 * 768 * 4;
  float* t1buf = (float*)p;    p += 256 * 768 * 4;

  dim3 ggrid(24, 32);
  cast_k<<<24576, 256, 0, stream>>>(inputs, xh);
  packT_k<<<dim3(24, 24), 256, 0, stream>>>(Wk, WkT);
  init_slots_k<<<768, 256, 0, stream>>>(slots0, slotsf);
  for (int it = 0; it < 3; ++it) {
    gemv_k<true, 0><<<ggrid, 256, 0, stream>>>(slotsf, Wq, bq, g_s, b_s, nullptr, nullptr, qbuf);
    gemv_k<false, 1><<<ggrid, 256, 0, stream>>>(qbuf, WkT, nullptr, nullptr, nullptr, nullptr,
                                                nullptr, qkbuf);
    qprep_k<<<64, 256, 0, stream>>>(qbuf, qkbuf, g_in, b_in, bk, Sqbuf, c0buf);
    dots_k<<<dim3(64, 32), 256, 0, stream>>>(xh, qkbuf, g_in, Sqbuf, c0buf, attnbuf, wbuf,
                                             rmubuf);
    pool_k<<<dim3(16, 32), 384, 0, stream>>>(xh, wbuf, partials);
    reduce_fix_k<<<256, 256, 0, stream>>>(partials, attnbuf, rmubuf, g_in, b_in, pooled,
                                          invbuf, rhobuf);
    gemv_k<false, 2><<<ggrid, 256, 0, stream>>>(pooled, Wv, bv, nullptr, nullptr, invbuf,
                                                rhobuf, updbuf);
    gemv_k<true, 3><<<ggrid, 256, 0, stream>>>(updbuf, W1, b1, g_ff, b_ff, nullptr, nullptr,
                                               t1buf);
    gemv_k<false, 4><<<ggrid, 256, 0, stream>>>(t1buf, W2, b2, nullptr, nullptr, nullptr,
                                                nullptr, slotsf);
  }
  out_slots_k<<<768, 256, 0, stream>>>(slotsf, (float*)d_out);
  out_attn_k<<<1024, 256, 0, stream>>>(attnbuf, invbuf, (float*)d_out);
}

// Round 11
// 544.765 us; speedup vs baseline: 1.9549x; 1.1134x over previous
//
#include <hip/hip_runtime.h>

#define LNEPS 1e-5f
#define AEPS 1e-8f
#define SCALE_Q 0.036084391824351615f  // 768^-0.5

typedef unsigned int uint32;

__device__ inline unsigned short bfb(float f) {
  __bf16 h = (__bf16)f;
  unsigned short u;
  __builtin_memcpy(&u, &h, 2);
  return u;
}

// ---------------- one-time: cast inputs fp32 -> packed bf16 (uint = 2 elems) ----------------
__global__ void cast_k(const float* __restrict__ in, uint32* __restrict__ xh) {
  size_t i = (size_t)blockIdx.x * 256 + threadIdx.x;  // 6291456 float4s
  float4 v = ((const float4*)in)[i];
  uint2 o;
  o.x = (uint32)bfb(v.x) | ((uint32)bfb(v.y) << 16);
  o.y = (uint32)bfb(v.z) | ((uint32)bfb(v.w) << 16);
  ((uint2*)xh)[i] = o;
}

// ---------------- transpose 768x768 fp32: WT[c][i] = W[i][c] ----------------
__global__ void packT_k(const float* __restrict__ W, float* __restrict__ WT) {
  __shared__ float tile[32][33];
  int c0 = blockIdx.x * 32, i0 = blockIdx.y * 32;
  int tx = threadIdx.x & 31, ty = threadIdx.x >> 5;  // 32x8
#pragma unroll
  for (int k = 0; k < 4; ++k)
    tile[ty + 8 * k][tx] = W[(size_t)(i0 + ty + 8 * k) * 768 + c0 + tx];
  __syncthreads();
#pragma unroll
  for (int k = 0; k < 4; ++k)
    WT[(size_t)(c0 + ty + 8 * k) * 768 + i0 + tx] = tile[tx][ty + 8 * k];
}

// ---------------- broadcast slots to all batch rows ----------------
__global__ void init_slots_k(const float* __restrict__ s0, float* __restrict__ slots) {
  int idx = blockIdx.x * 256 + threadIdx.x;  // 196608
  slots[idx] = s0[idx % 6144];
}

// ---------------- generic batched GEMV, grid (24 colblk, 32 rowblk), 256 thr ----------------
// 8 rows x 32 cols per block; thread: cx=t&7 (4 cols), rw=(t>>3)&7, kg=t>>6 (192 k each).
// MODE 0: acc+bias | 1: acc | 2: alpha[r]*acc+beta[r]*bias | 3: relu(acc+bias) | 4: out+=acc+bias
template <bool LN, int MODE>
__global__ void gemv_k(const float* __restrict__ X, const float* __restrict__ W,
                       const float* __restrict__ bias, const float* __restrict__ gamma,
                       const float* __restrict__ beta_ln, const float* __restrict__ alpha,
                       const float* __restrict__ beta, float* __restrict__ out) {
  __shared__ float Xs[8][772];
  __shared__ float sm[8], sr[8];
  int c0 = blockIdx.x * 32, r0 = blockIdx.y * 8, t = threadIdx.x;
#pragma unroll
  for (int j = 0; j < 6; ++j) {
    int fidx = j * 256 + t;  // 1536 float4s
    int r = fidx / 192, c4 = fidx % 192;
    *(float4*)&Xs[r][c4 * 4] = *(const float4*)(X + (size_t)(r0 + r) * 768 + c4 * 4);
  }
  __syncthreads();
  if (LN) {
    int w = t >> 6, l = t & 63;
#pragma unroll
    for (int jr = 0; jr < 2; ++jr) {
      int r = w + 4 * jr;
      float s = 0.f, ss = 0.f;
#pragma unroll
      for (int m2 = 0; m2 < 12; ++m2) { float x = Xs[r][l + 64 * m2]; s += x; ss += x * x; }
#pragma unroll
      for (int o = 32; o; o >>= 1) { s += __shfl_xor(s, o); ss += __shfl_xor(ss, o); }
      if (l == 0) {
        float mu = s * (1.f / 768.f);
        sm[r] = mu;
        sr[r] = rsqrtf(ss * (1.f / 768.f) - mu * mu + LNEPS);
      }
    }
    __syncthreads();
#pragma unroll
    for (int j = 0; j < 24; ++j) {
      int idx = j * 256 + t;  // 6144
      int r = idx / 768, d = idx % 768;
      Xs[r][d] = (Xs[r][d] - sm[r]) * sr[r] * gamma[d] + beta_ln[d];
    }
    __syncthreads();
  }
  int cx = t & 7, rw = (t >> 3) & 7, kg = t >> 6;
  int c = c0 + cx * 4;
  float ax = 0.f, ay = 0.f, az = 0.f, aw = 0.f;
  const float* wp = W + c;
  int k0 = kg * 192;
  for (int k = k0; k < k0 + 192; k += 4) {
#pragma unroll
    for (int kk = 0; kk < 4; ++kk) {
      float4 wv = *(const float4*)(wp + (size_t)(k + kk) * 768);
      float xv = Xs[rw][k + kk];
      ax += xv * wv.x; ay += xv * wv.y; az += xv * wv.z; aw += xv * wv.w;
    }
  }
  __syncthreads();  // all kg done reading Xs; reuse as reduce buffer
  float* red = (float*)Xs;
  if (kg > 0) {
    float4 v; v.x = ax; v.y = ay; v.z = az; v.w = aw;
    *(float4*)&red[(size_t)(((kg - 1) * 64 + rw * 8 + cx)) * 4] = v;
  }
  __syncthreads();
  if (kg == 0) {
#pragma unroll
    for (int g = 1; g < 4; ++g) {
      float4 v = *(const float4*)&red[(size_t)(((g - 1) * 64 + rw * 8 + cx)) * 4];
      ax += v.x; ay += v.y; az += v.z; aw += v.w;
    }
    int rr = r0 + rw;
    size_t oidx = (size_t)rr * 768 + c;
    float4 res;
    if (MODE == 0) {
      float4 b4 = *(const float4*)(bias + c);
      res.x = ax + b4.x; res.y = ay + b4.y; res.z = az + b4.z; res.w = aw + b4.w;
    } else if (MODE == 1) {
      res.x = ax; res.y = ay; res.z = az; res.w = aw;
    } else if (MODE == 2) {
      float4 b4 = *(const float4*)(bias + c);
      float al = alpha[rr], be = beta[rr];
      res.x = ax * al + b4.x * be; res.y = ay * al + b4.y * be;
      res.z = az * al + b4.z * be; res.w = aw * al + b4.w * be;
    } else if (MODE == 3) {
      float4 b4 = *(const float4*)(bias + c);
      res.x = fmaxf(ax + b4.x, 0.f); res.y = fmaxf(ay + b4.y, 0.f);
      res.z = fmaxf(az + b4.z, 0.f); res.w = fmaxf(aw + b4.w, 0.f);
    } else {
      float4 b4 = *(const float4*)(bias + c);
      float4 old = *(const float4*)(out + oidx);
      res.x = old.x + ax + b4.x; res.y = old.y + ay + b4.y;
      res.z = old.z + az + b4.z; res.w = old.w + aw + b4.w;
    }
    *(float4*)(out + oidx) = res;
  }
}

// ---------------- per-slot scalars: Sq = qk.g_in ; c0 = qk.b_in + q.bk ----------------
__global__ void qprep_k(const float* __restrict__ q, const float* __restrict__ qk,
                        const float* __restrict__ g_in, const float* __restrict__ b_in,
                        const float* __restrict__ bk, float* __restrict__ Sqbuf,
                        float* __restrict__ c0buf) {
  int row = blockIdx.x * 4 + (threadIdx.x >> 6), l = threadIdx.x & 63;
  float aS = 0.f, aC = 0.f;
#pragma unroll
  for (int j = 0; j < 12; ++j) {
    int d = l + 64 * j;
    float qkv = qk[(size_t)row * 768 + d];
    aS += qkv * g_in[d];
    aC += qkv * b_in[d] + q[(size_t)row * 768 + d] * bk[d];
  }
#pragma unroll
  for (int o = 32; o; o >>= 1) { aS += __shfl_xor(aS, o); aC += __shfl_xor(aC, o); }
  if (l == 0) { Sqbuf[row] = aS; c0buf[row] = aC; }
}

// ---------------- dots+softmax over packed-bf16 x; attn, w=a*r, rmu=r*mu ----------------
// grid (64 chunk, 32 b), 256 thr = 4 waves x 4 rows. VGPR cap 256 (no spill possible);
// outputs parked in LDS, one coalesced block store at the end (no sub-line scatter).
__global__ void __launch_bounds__(256, 2)
dots_k(const uint32* __restrict__ xh, const float* __restrict__ qk,
       const float* __restrict__ g_in, const float* __restrict__ Sqbuf,
       const float* __restrict__ c0buf, float* __restrict__ attnbuf,
       float* __restrict__ wbuf, float* __restrict__ rmubuf) {
  __shared__ float qkgs[8][768];
  __shared__ float c0s[8], Sqs[8];
  __shared__ float oa[16][8], ow[16][8], orm[16];
  int chunk = blockIdx.x, b = blockIdx.y, t = threadIdx.x, w = t >> 6, l = t & 63;
#pragma unroll
  for (int s2 = 0; s2 < 8; ++s2)
    for (int d = t; d < 768; d += 256)
      qkgs[s2][d] = qk[(size_t)b * 6144 + s2 * 768 + d] * g_in[d];
  if (t < 8) { c0s[t] = c0buf[b * 8 + t]; Sqs[t] = Sqbuf[b * 8 + t]; }
  __syncthreads();
  for (int rr = 0; rr < 4; ++rr) {
    int lr = w * 4 + rr;                       // local row 0..15
    size_t row = (size_t)b * 1024 + chunk * 16 + lr;
    const uint32* xr = xh + row * 384;
    float s = 0.f, ss = 0.f, ds[8] = {};
#pragma unroll
    for (int j = 0; j < 6; ++j) {
      uint32 u = xr[l + 64 * j];
      float a = __uint_as_float(u << 16);
      float bv = __uint_as_float(u & 0xffff0000u);
      s += a + bv;
      ss += a * a + bv * bv;
      int d0 = 2 * (l + 64 * j);
#pragma unroll
      for (int s2 = 0; s2 < 8; ++s2) {
        float2 qg = *(const float2*)&qkgs[s2][d0];
        ds[s2] += qg.x * a + qg.y * bv;
      }
    }
#pragma unroll
    for (int o = 32; o; o >>= 1) {
      s += __shfl_xor(s, o);
      ss += __shfl_xor(ss, o);
#pragma unroll
      for (int s2 = 0; s2 < 8; ++s2) ds[s2] += __shfl_xor(ds[s2], o);
    }
    float mu = s * (1.f / 768.f), r = rsqrtf(ss * (1.f / 768.f) - mu * mu + LNEPS);
    float rmu = r * mu;
    float sc[8];
#pragma unroll
    for (int s2 = 0; s2 < 8; ++s2)
      sc[s2] = (r * ds[s2] - rmu * Sqs[s2] + c0s[s2]) * SCALE_Q;
    float mx = sc[0];
#pragma unroll
    for (int s2 = 1; s2 < 8; ++s2) mx = fmaxf(mx, sc[s2]);
    float e[8], se = 0.f;
#pragma unroll
    for (int s2 = 0; s2 < 8; ++s2) { e[s2] = __expf(sc[s2] - mx); se += e[s2]; }
    float inv_se = 1.f / se;
    float a = e[0];
#pragma unroll
    for (int s2 = 1; s2 < 8; ++s2) a = (l == s2) ? e[s2] : a;
    a *= inv_se;
    if (l < 8) {
      oa[lr][l] = a;
      ow[lr][l] = a * r;
    }
    if (l == 8) orm[lr] = rmu;
  }
  __syncthreads();
  size_t base8 = ((size_t)b * 1024 + chunk * 16) * 8;
  if (t < 128) {
    attnbuf[base8 + t] = oa[t >> 3][t & 7];
    wbuf[base8 + t] = ow[t >> 3][t & 7];
    if (t < 16) rmubuf[(size_t)b * 1024 + chunk * 16 + t] = orm[t];
  }
}

// ---------------- pool packed-bf16 x with weights w -> partials[chunk][b*8+s][768] -------
// grid (16 chunk, 32 b), 384 thr: thread owns packed col t (d=2t,2t+1)
__global__ void pool_k(const uint32* __restrict__ xh, const float* __restrict__ wbuf,
                       float* __restrict__ partials) {
  __shared__ float ws[64][8];
  int chunk = blockIdx.x, b = blockIdx.y, t = threadIdx.x;
  for (int i = t; i < 512; i += 384)
    ((float*)ws)[i] = wbuf[((size_t)b * 1024 + chunk * 64) * 8 + i];
  __syncthreads();
  float acc[8][2] = {};
  const uint32* xp = xh + ((size_t)b * 1024 + chunk * 64) * 384;
  for (int nn = 0; nn < 64; ++nn) {
    uint32 u = xp[(size_t)nn * 384 + t];
    float x0 = __uint_as_float(u << 16);
    float x1 = __uint_as_float(u & 0xffff0000u);
#pragma unroll
    for (int s2 = 0; s2 < 8; ++s2) {
      float wv = ws[nn][s2];
      acc[s2][0] += wv * x0; acc[s2][1] += wv * x1;
    }
  }
#pragma unroll
  for (int s2 = 0; s2 < 8; ++s2) {
    size_t base = ((size_t)(chunk * 256 + b * 8 + s2)) * 768;
    float2 v; v.x = acc[s2][0]; v.y = acc[s2][1];
    *(float2*)&partials[base + 2 * t] = v;
  }
}

// ---------------- reduce partials + A0/A1 + LN-fixup -> pooled ; inv, rho ----------------
// grid 256 (row = b*8+s), 256 thr
__global__ void reduce_fix_k(const float* __restrict__ partials, const float* __restrict__ attnbuf,
                             const float* __restrict__ rmubuf, const float* __restrict__ g_in,
                             const float* __restrict__ b_in, float* __restrict__ pooled,
                             float* __restrict__ invbuf, float* __restrict__ rhobuf) {
  __shared__ float rA[4], rB[4], sAB[2];
  int row = blockIdx.x, t = threadIdx.x;  // row = b*8+s
  int b = row >> 3, sl = row & 7;
  float a0 = 0.f, a1 = 0.f;
#pragma unroll
  for (int j = 0; j < 4; ++j) {
    int n = t + 256 * j;
    float a = attnbuf[((size_t)b * 1024 + n) * 8 + sl];
    a0 += a;
    a1 += a * rmubuf[b * 1024 + n];
  }
#pragma unroll
  for (int o = 32; o; o >>= 1) { a0 += __shfl_xor(a0, o); a1 += __shfl_xor(a1, o); }
  if ((t & 63) == 0) { rA[t >> 6] = a0; rB[t >> 6] = a1; }
  __syncthreads();
  if (t == 0) {
    sAB[0] = rA[0] + rA[1] + rA[2] + rA[3];
    sAB[1] = rB[0] + rB[1] + rB[2] + rB[3];
  }
  __syncthreads();
  float A0 = sAB[0], A1 = sAB[1];
#pragma unroll
  for (int c = 0; c < 3; ++c) {
    int d = t + 256 * c;
    float a = 0.f;
    for (int ch = 0; ch < 16; ++ch) a += partials[((size_t)(ch * 256 + row)) * 768 + d];
    pooled[(size_t)row * 768 + d] = g_in[d] * (a - A1) + b_in[d] * A0;
  }
  if (t == 0) {
    float iv = 1.f / (A0 + AEPS);
    invbuf[row] = iv;
    rhobuf[row] = A0 * iv;
  }
}

// ---------------- output writers (fp32) ----------------
__global__ void out_slots_k(const float* __restrict__ slots, float* __restrict__ out) {
  int i = blockIdx.x * 256 + threadIdx.x;  // 196608
  out[i] = slots[i];
}
__global__ void out_attn_k(const float* __restrict__ attnbuf, const float* __restrict__ invbuf,
                           float* __restrict__ out) {
  int i = blockIdx.x * 256 + threadIdx.x;  // 262144 ; layout [b][n][s]
  out[196608 + i] = attnbuf[i] * invbuf[((i >> 13) << 3) + (i & 7)];
}

extern "C" void kernel_launch(void* const* d_in, const int* in_sizes, int n_in,
                              void* d_out, int out_size, void* d_ws, size_t ws_size,
                              hipStream_t stream) {
  (void)in_sizes; (void)n_in; (void)out_size; (void)ws_size;
  const float* slots0 = (const float*)d_in[0];
  const float* inputs = (const float*)d_in[1];
  const float* Wq = (const float*)d_in[2];
  const float* bq = (const float*)d_in[3];
  const float* Wk = (const float*)d_in[4];
  const float* bk = (const float*)d_in[5];
  const float* Wv = (const float*)d_in[6];
  const float* bv = (const float*)d_in[7];
  const float* g_in = (const float*)d_in[8];
  const float* b_in = (const float*)d_in[9];
  const float* g_s = (const float*)d_in[10];
  const float* b_s = (const float*)d_in[11];
  const float* g_ff = (const float*)d_in[12];
  const float* b_ff = (const float*)d_in[13];
  const float* W1 = (const float*)d_in[14];
  const float* b1 = (const float*)d_in[15];
  const float* W2 = (const float*)d_in[16];
  const float* b2 = (const float*)d_in[17];

  char* p = (char*)d_ws;
  uint32* xh = (uint32*)p;     p += (size_t)32768 * 384 * 4;  // packed bf16 inputs
  float* WkT = (float*)p;      p += (size_t)768 * 768 * 4;
  float* slotsf = (float*)p;   p += 256 * 768 * 4;
  float* qbuf = (float*)p;     p += 256 * 768 * 4;
  float* qkbuf = (float*)p;    p += 256 * 768 * 4;
  float* Sqbuf = (float*)p;    p += 256 * 4;
  float* c0buf = (float*)p;    p += 256 * 4;
  float* attnbuf = (float*)p;  p += (size_t)32768 * 8 * 4;
  float* wbuf = (float*)p;     p += (size_t)32768 * 8 * 4;
  float* rmubuf = (float*)p;   p += 32768 * 4;
  float* partials = (float*)p; p += (size_t)16 * 256 * 768 * 4;
  float* pooled = (float*)p;   p += 256 * 768 * 4;
  float* invbuf = (float*)p;   p += 256 * 4;
  float* rhobuf = (float*)p;   p += 256 * 4;
  float* updbuf = (float*)p;   p += 256 * 768 * 4;
  float* t1buf = (float*)p;    p += 256 * 768 * 4;

  dim3 ggrid(24, 32);
  cast_k<<<24576, 256, 0, stream>>>(inputs, xh);
  packT_k<<<dim3(24, 24), 256, 0, stream>>>(Wk, WkT);
  init_slots_k<<<768, 256, 0, stream>>>(slots0, slotsf);
  for (int it = 0; it < 3; ++it) {
    gemv_k<true, 0><<<ggrid, 256, 0, stream>>>(slotsf, Wq, bq, g_s, b_s, nullptr, nullptr, qbuf);
    gemv_k<false, 1><<<ggrid, 256, 0, stream>>>(qbuf, WkT, nullptr, nullptr, nullptr, nullptr,
                                                nullptr, qkbuf);
    qprep_k<<<64, 256, 0, stream>>>(qbuf, qkbuf, g_in, b_in, bk, Sqbuf, c0buf);
    dots_k<<<dim3(64, 32), 256, 0, stream>>>(xh, qkbuf, g_in, Sqbuf, c0buf, attnbuf, wbuf,
                                             rmubuf);
    pool_k<<<dim3(16, 32), 384, 0, stream>>>(xh, wbuf, partials);
    reduce_fix_k<<<256, 256, 0, stream>>>(partials, attnbuf, rmubuf, g_in, b_in, pooled,
                                          invbuf, rhobuf);
    gemv_k<false, 2><<<ggrid, 256, 0, stream>>>(pooled, Wv, bv, nullptr, nullptr, invbuf,
                                                rhobuf, updbuf);
    gemv_k<true, 3><<<ggrid, 256, 0, stream>>>(updbuf, W1, b1, g_ff, b_ff, nullptr, nullptr,
                                               t1buf);
    gemv_k<false, 4><<<ggrid, 256, 0, stream>>>(t1buf, W2, b2, nullptr, nullptr, nullptr,
                                                nullptr, slotsf);
  }
  out_slots_k<<<768, 256, 0, stream>>>(slotsf, (float*)d_out);
  out_attn_k<<<1024, 256, 0, stream>>>(attnbuf, invbuf, (float*)d_out);
}